// Round 3
// baseline (363.978 us; speedup 1.0000x reference)
//
#include <hip/hip_runtime.h>
#include <hip/hip_bf16.h>

// BEV pool v2 via fixed-size point chunks + run-flush atomics.
// Thread = (chunk of 16 sorted points, channel-quad). ranks_bevs is sorted,
// so each chunk covers few BEV runs; flush a run's partial sum with atomics.

#define C_CH  80
#define CPT   20   // channel-quads per point row (80/4)
#define CHUNK 16   // points per thread

__global__ void bev_pool_chunk_kernel(
    const float*  __restrict__ depth,   // flat depth table
    const float4* __restrict__ feat4,   // feat rows as [n_rows][20] float4
    const int*    __restrict__ rd,      // ranks_depth [P]
    const int*    __restrict__ rf,      // ranks_feat  [P]
    const int*    __restrict__ rb,      // ranks_bev   [P] (sorted)
    int P,
    int n_bev,                          // 16384
    float* __restrict__ out)            // [80][n_bev]
{
    int idx = blockIdx.x * blockDim.x + threadIdx.x;
    int n_chunks = (P + CHUNK - 1) / CHUNK;
    if (idx >= n_chunks * CPT) return;

    int chunk = idx / CPT;
    int c4    = idx - chunk * CPT;      // 0..19 — lanes 0..19 share a chunk
    int p0    = chunk * CHUNK;
    int pend  = min(p0 + CHUNK, P);

    float4 acc = make_float4(0.f, 0.f, 0.f, 0.f);
    int cur = rb[p0];
    long obase = (long)(c4 * 4) * n_bev;

#define FLUSH(BEV) do { \
        atomicAdd(out + obase + (BEV), acc.x); \
        atomicAdd(out + obase + (long)n_bev + (BEV), acc.y); \
        atomicAdd(out + obase + 2L * n_bev + (BEV), acc.z); \
        atomicAdd(out + obase + 3L * n_bev + (BEV), acc.w); \
        acc = make_float4(0.f, 0.f, 0.f, 0.f); \
    } while (0)

    int p = p0;
    for (; p + 4 <= pend; p += 4) {
        int4 rd4 = *reinterpret_cast<const int4*>(rd + p);
        int4 rf4 = *reinterpret_cast<const int4*>(rf + p);
        int4 rb4 = *reinterpret_cast<const int4*>(rb + p);
        float  d0 = depth[rd4.x], d1 = depth[rd4.y], d2 = depth[rd4.z], d3 = depth[rd4.w];
        float4 f0 = feat4[(long)rf4.x * CPT + c4];
        float4 f1 = feat4[(long)rf4.y * CPT + c4];
        float4 f2 = feat4[(long)rf4.z * CPT + c4];
        float4 f3 = feat4[(long)rf4.w * CPT + c4];

        if (rb4.x != cur) { FLUSH(cur); cur = rb4.x; }
        acc.x += d0 * f0.x; acc.y += d0 * f0.y; acc.z += d0 * f0.z; acc.w += d0 * f0.w;
        if (rb4.y != cur) { FLUSH(cur); cur = rb4.y; }
        acc.x += d1 * f1.x; acc.y += d1 * f1.y; acc.z += d1 * f1.z; acc.w += d1 * f1.w;
        if (rb4.z != cur) { FLUSH(cur); cur = rb4.z; }
        acc.x += d2 * f2.x; acc.y += d2 * f2.y; acc.z += d2 * f2.z; acc.w += d2 * f2.w;
        if (rb4.w != cur) { FLUSH(cur); cur = rb4.w; }
        acc.x += d3 * f3.x; acc.y += d3 * f3.y; acc.z += d3 * f3.z; acc.w += d3 * f3.w;
    }
    for (; p < pend; ++p) {
        int b = rb[p];
        float  d = depth[rd[p]];
        float4 f = feat4[(long)rf[p] * CPT + c4];
        if (b != cur) { FLUSH(cur); cur = b; }
        acc.x += d * f.x; acc.y += d * f.y; acc.z += d * f.z; acc.w += d * f.w;
    }
    FLUSH(cur);
#undef FLUSH
}

extern "C" void kernel_launch(void* const* d_in, const int* in_sizes, int n_in,
                              void* d_out, int out_size, void* d_ws, size_t ws_size,
                              hipStream_t stream) {
    const float*  depth = (const float*)d_in[0];
    const float4* feat4 = (const float4*)d_in[1];
    const int* ranks_depth = (const int*)d_in[2];
    const int* ranks_feat  = (const int*)d_in[3];
    const int* ranks_bev   = (const int*)d_in[4];
    // d_in[5] = bev_feat_shape; d_in[6]/[7] = interval metadata (unused now).

    int P = in_sizes[2];                  // 1,000,000
    int n_bev = out_size / C_CH;          // 16384
    float* out = (float*)d_out;

    // Zero the output: atomics accumulate into it (harness poisons 0xAA).
    hipMemsetAsync(d_out, 0, (size_t)out_size * sizeof(float), stream);

    int n_chunks = (P + CHUNK - 1) / CHUNK;
    int total = n_chunks * CPT;
    int block = 256;
    int grid = (total + block - 1) / block;
    bev_pool_chunk_kernel<<<grid, block, 0, stream>>>(
        depth, feat4, ranks_depth, ranks_feat, ranks_bev, P, n_bev, out);
}

// Round 5
// 134.885 us; speedup vs baseline: 2.6984x; 2.6984x over previous
//
#include <hip/hip_runtime.h>
#include <hip/hip_bf16.h>

// BEV pool v2: interval ownership (no atomics) + 8-way point-split per
// interval with LDS combine. Thread = (interval, channel-quad, split).
// 320-thread block = 2 intervals x 20 quads x 8 splits.

#define C_CH   80
#define QPT    20   // float4 quads per feat row (80/4)
#define SPLITS 8
#define IPB    2    // intervals per block
#define BLOCK  (IPB * QPT * SPLITS)  // 320

__global__ __launch_bounds__(BLOCK) void bev_pool_split_kernel(
    const float*  __restrict__ depth,
    const float4* __restrict__ feat4,   // rows [n_rows][20] float4
    const int*    __restrict__ rd,
    const int*    __restrict__ rf,
    const int*    __restrict__ rb,      // sorted
    const int*    __restrict__ istart,
    const int*    __restrict__ ilen,
    int n_intervals,
    int n_bev,                          // 16384
    float* __restrict__ out)            // [80][n_bev]
{
    __shared__ float4 red[IPB][SPLITS][QPT];

    int tid   = threadIdx.x;
    int il    = tid / (QPT * SPLITS);   // 0..IPB-1
    int r     = tid - il * (QPT * SPLITS);
    int split = r / QPT;                // 0..7
    int quad  = r - split * QPT;        // 0..19
    int interval = blockIdx.x * IPB + il;
    bool valid = interval < n_intervals;

    float4 acc = make_float4(0.f, 0.f, 0.f, 0.f);
    int start = 0, len = 0, bev = 0;

    if (valid) {
        start = istart[interval];
        len   = ilen[interval];
        bev   = rb[start];

        int i = split;
        // two points in flight per thread
        for (; i + SPLITS < len; i += 2 * SPLITS) {
            int p0 = start + i;
            int p1 = p0 + SPLITS;
            int rd0 = rd[p0], rf0 = rf[p0];
            int rd1 = rd[p1], rf1 = rf[p1];
            float d0 = depth[rd0];
            float d1 = depth[rd1];
            float4 f0 = feat4[(long)rf0 * QPT + quad];
            float4 f1 = feat4[(long)rf1 * QPT + quad];
            acc.x += d0 * f0.x; acc.y += d0 * f0.y;
            acc.z += d0 * f0.z; acc.w += d0 * f0.w;
            acc.x += d1 * f1.x; acc.y += d1 * f1.y;
            acc.z += d1 * f1.z; acc.w += d1 * f1.w;
        }
        if (i < len) {
            int p = start + i;
            float d = depth[rd[p]];
            float4 f = feat4[(long)rf[p] * QPT + quad];
            acc.x += d * f.x; acc.y += d * f.y;
            acc.z += d * f.z; acc.w += d * f.w;
        }
    }

    red[il][split][quad] = acc;
    __syncthreads();

    if (valid && split == 0) {
        float4 s = acc;
        #pragma unroll
        for (int k = 1; k < SPLITS; ++k) {
            float4 t = red[il][k][quad];
            s.x += t.x; s.y += t.y; s.z += t.z; s.w += t.w;
        }
        long o = (long)(quad * 4) * n_bev + bev;
        out[o]             = s.x;
        out[o + n_bev]     = s.y;
        out[o + 2L * n_bev] = s.z;
        out[o + 3L * n_bev] = s.w;
    }
}

extern "C" void kernel_launch(void* const* d_in, const int* in_sizes, int n_in,
                              void* d_out, int out_size, void* d_ws, size_t ws_size,
                              hipStream_t stream) {
    const float*  depth = (const float*)d_in[0];
    const float4* feat4 = (const float4*)d_in[1];
    const int* ranks_depth = (const int*)d_in[2];
    const int* ranks_feat  = (const int*)d_in[3];
    const int* ranks_bev   = (const int*)d_in[4];
    // d_in[5] = bev_feat_shape (unused, shapes static)
    const int* interval_starts  = (const int*)d_in[6];
    const int* interval_lengths = (const int*)d_in[7];

    int n_intervals = in_sizes[6];
    int n_bev = out_size / C_CH;          // 16384
    float* out = (float*)d_out;

    // Zero output: uncovered BEV cells must be 0 (harness poisons 0xAA).
    hipMemsetAsync(d_out, 0, (size_t)out_size * sizeof(float), stream);

    int grid = (n_intervals + IPB - 1) / IPB;
    bev_pool_split_kernel<<<grid, BLOCK, 0, stream>>>(
        depth, feat4, ranks_depth, ranks_feat, ranks_bev,
        interval_starts, interval_lengths, n_intervals, n_bev, out);
}

// Round 6
// 133.710 us; speedup vs baseline: 2.7222x; 1.0088x over previous
//
#include <hip/hip_runtime.h>
#include <hip/hip_bf16.h>

// BEV pool v2, two-kernel version:
//  K1: dgath[p] = depth[rd[p]]  (random depth probes done exactly once)
//  K2: interval-owned accumulation, channel-halved + XCD-aware block
//      placement so each XCD's feat slice (40ch = 2.7MB) is L2-resident.

#define C_CH   80
#define QPT    20       // float4 quads per feat row
#define HQ     10       // quads per channel-half
#define SPLITS 8
#define IPB    4        // intervals per block
#define BLOCK  (IPB * SPLITS * HQ)   // 320
#define CLUST  (IPB * 4)             // intervals per 8-block cluster (16)

__global__ void depth_gather_kernel(const float* __restrict__ depth,
                                    const int*   __restrict__ rd,
                                    float* __restrict__ dgath, int P) {
    int i = blockIdx.x * blockDim.x + threadIdx.x;
    if (i < P) dgath[i] = depth[rd[i]];
}

template <bool USE_DG>
__global__ __launch_bounds__(BLOCK) void bev_pool_main_kernel(
    const float*  __restrict__ depth,
    const float*  __restrict__ dgath,
    const int*    __restrict__ rd,
    const float4* __restrict__ feat4,   // rows [n_rows][20] float4
    const int*    __restrict__ rf,
    const int*    __restrict__ rb,      // sorted
    const int*    __restrict__ istart,
    const int*    __restrict__ ilen,
    int n_intervals,
    int n_bev,                          // 16384
    float* __restrict__ out)            // [80][n_bev]
{
    __shared__ float4 red[IPB][SPLITS][HQ];

    int bid     = blockIdx.x;
    int slot    = bid & 7;              // presumed XCD (round-robin dispatch)
    int cluster = bid >> 3;
    int half    = slot >> 2;            // 0 -> ch 0..39, 1 -> ch 40..79
    int quarter = slot & 3;
    int ibase   = cluster * CLUST + quarter * IPB;

    int tid   = threadIdx.x;
    int il    = tid / (SPLITS * HQ);    // 0..3
    int r     = tid - il * (SPLITS * HQ);
    int split = r / HQ;                 // 0..7
    int q     = r - split * HQ;         // 0..9
    int gq    = half * HQ + q;          // global quad 0..19

    int interval = ibase + il;
    bool valid = interval < n_intervals;

    float4 acc = make_float4(0.f, 0.f, 0.f, 0.f);
    int bev = 0;

    if (valid) {
        int start = istart[interval];
        int len   = ilen[interval];
        bev = rb[start];

        int i = split;
        for (; i + SPLITS < len; i += 2 * SPLITS) {
            int p0 = start + i;
            int p1 = p0 + SPLITS;
            float d0 = USE_DG ? dgath[p0] : depth[rd[p0]];
            float d1 = USE_DG ? dgath[p1] : depth[rd[p1]];
            int rf0 = rf[p0], rf1 = rf[p1];
            float4 f0 = feat4[(long)rf0 * QPT + gq];
            float4 f1 = feat4[(long)rf1 * QPT + gq];
            acc.x += d0 * f0.x; acc.y += d0 * f0.y;
            acc.z += d0 * f0.z; acc.w += d0 * f0.w;
            acc.x += d1 * f1.x; acc.y += d1 * f1.y;
            acc.z += d1 * f1.z; acc.w += d1 * f1.w;
        }
        if (i < len) {
            int p = start + i;
            float d = USE_DG ? dgath[p] : depth[rd[p]];
            float4 f = feat4[(long)rf[p] * QPT + gq];
            acc.x += d * f.x; acc.y += d * f.y;
            acc.z += d * f.z; acc.w += d * f.w;
        }
    }

    red[il][split][q] = acc;
    __syncthreads();

    if (valid && split == 0) {
        float4 s = acc;
        #pragma unroll
        for (int k = 1; k < SPLITS; ++k) {
            float4 t = red[il][k][q];
            s.x += t.x; s.y += t.y; s.z += t.z; s.w += t.w;
        }
        long o = (long)(gq * 4) * n_bev + bev;
        out[o]              = s.x;
        out[o + n_bev]      = s.y;
        out[o + 2L * n_bev] = s.z;
        out[o + 3L * n_bev] = s.w;
    }
}

extern "C" void kernel_launch(void* const* d_in, const int* in_sizes, int n_in,
                              void* d_out, int out_size, void* d_ws, size_t ws_size,
                              hipStream_t stream) {
    const float*  depth = (const float*)d_in[0];
    const float4* feat4 = (const float4*)d_in[1];
    const int* ranks_depth = (const int*)d_in[2];
    const int* ranks_feat  = (const int*)d_in[3];
    const int* ranks_bev   = (const int*)d_in[4];
    // d_in[5] = bev_feat_shape (static)
    const int* interval_starts  = (const int*)d_in[6];
    const int* interval_lengths = (const int*)d_in[7];

    int P = in_sizes[2];
    int n_intervals = in_sizes[6];
    int n_bev = out_size / C_CH;          // 16384
    float* out = (float*)d_out;
    float* dgath = (float*)d_ws;

    // Zero output: uncovered BEV cells must read 0 (harness poisons 0xAA).
    hipMemsetAsync(d_out, 0, (size_t)out_size * sizeof(float), stream);

    bool use_dg = ws_size >= (size_t)P * sizeof(float);
    if (use_dg) {
        int gblock = 256;
        int ggrid = (P + gblock - 1) / gblock;
        depth_gather_kernel<<<ggrid, gblock, 0, stream>>>(depth, ranks_depth, dgath, P);
    }

    int clusters = (n_intervals + CLUST - 1) / CLUST;
    int grid = clusters * 8;
    if (use_dg) {
        bev_pool_main_kernel<true><<<grid, BLOCK, 0, stream>>>(
            depth, dgath, ranks_depth, feat4, ranks_feat, ranks_bev,
            interval_starts, interval_lengths, n_intervals, n_bev, out);
    } else {
        bev_pool_main_kernel<false><<<grid, BLOCK, 0, stream>>>(
            depth, dgath, ranks_depth, feat4, ranks_feat, ranks_bev,
            interval_starts, interval_lengths, n_intervals, n_bev, out);
    }
}

// Round 7
// 117.569 us; speedup vs baseline: 3.0959x; 1.1373x over previous
//
#include <hip/hip_runtime.h>
#include <hip/hip_bf16.h>

// BEV pool v2, round 7:
//  prep: (a) feat fp32 -> bf16 table (RTNE) in ws: row = 80ch * 2B = 160B,
//            whole table 2.7MB -> L2-resident on every XCD.
//        (b) dgath[p] = depth[rd[p]] (random depth probes done once).
//  main: thread = (interval, split, lane10). lane10 covers 8 channels via one
//        16B bf16x8 gather. Indices/dgath read once per point. LDS combine
//        across 8 splits, exclusive store per interval (no atomics).

#define C_CH   80
#define NL     10                    // lanes per point row (8 ch each)
#define SPLITS 8
#define IPB    4
#define BLOCK  (IPB * SPLITS * NL)   // 320

__global__ void prep_kernel(const float*  __restrict__ depth,
                            const int*    __restrict__ rd,
                            const float4* __restrict__ feat4,
                            float* __restrict__ dgath,
                            uint2* __restrict__ fbf,   // 4 bf16 per uint2
                            int P, int NF4) {
    int i = blockIdx.x * blockDim.x + threadIdx.x;
    if (i < NF4) {
        float4 v = feat4[i];
        float f[4] = {v.x, v.y, v.z, v.w};
        unsigned h[4];
        #pragma unroll
        for (int k = 0; k < 4; ++k) {
            unsigned u = __float_as_uint(f[k]);
            h[k] = (u + 0x7fffu + ((u >> 16) & 1u)) >> 16;   // RTNE
        }
        uint2 o;
        o.x = h[0] | (h[1] << 16);
        o.y = h[2] | (h[3] << 16);
        fbf[i] = o;
    }
    if (i < P) dgath[i] = depth[rd[i]];
}

__device__ __forceinline__ void bf8_fma(float acc[8], float d, int4 w) {
    unsigned v[4] = {(unsigned)w.x, (unsigned)w.y, (unsigned)w.z, (unsigned)w.w};
    #pragma unroll
    for (int k = 0; k < 4; ++k) {
        float lo = __uint_as_float(v[k] << 16);
        float hi = __uint_as_float(v[k] & 0xffff0000u);
        acc[2 * k]     += d * lo;
        acc[2 * k + 1] += d * hi;
    }
}

template <bool FAST>
__global__ __launch_bounds__(BLOCK) void bev_main(
    const float*  __restrict__ depth,
    const int*    __restrict__ rd,
    const float*  __restrict__ dgath,
    const int4*   __restrict__ fbf,     // bf16 rows, 10 x 16B granules/row
    const float4* __restrict__ featf,   // fp32 fallback, 20 granules/row
    const int*    __restrict__ rf,
    const int*    __restrict__ rb,      // sorted
    const int*    __restrict__ istart,
    const int*    __restrict__ ilen,
    int n_intervals,
    int n_bev,                          // 16384
    float* __restrict__ out)            // [80][n_bev]
{
    __shared__ float red[IPB][SPLITS][NL][9];  // pad 9 to spread banks

    int tid   = threadIdx.x;
    int il    = tid / (SPLITS * NL);
    int r     = tid - il * (SPLITS * NL);
    int split = r / NL;
    int l10   = r - split * NL;          // 0..9
    int interval = blockIdx.x * IPB + il;
    bool valid = interval < n_intervals;

    float acc[8] = {0.f, 0.f, 0.f, 0.f, 0.f, 0.f, 0.f, 0.f};
    int bev = 0;

    if (valid) {
        int start = istart[interval];
        int len   = ilen[interval];
        bev = rb[start];

        int i = split;
        for (; i + SPLITS < len; i += 2 * SPLITS) {
            int p0 = start + i;
            int p1 = p0 + SPLITS;
            float d0 = FAST ? dgath[p0] : depth[rd[p0]];
            float d1 = FAST ? dgath[p1] : depth[rd[p1]];
            int q0 = rf[p0], q1 = rf[p1];
            if (FAST) {
                int4 w0 = fbf[(long)q0 * NL + l10];
                int4 w1 = fbf[(long)q1 * NL + l10];
                bf8_fma(acc, d0, w0);
                bf8_fma(acc, d1, w1);
            } else {
                float4 a0 = featf[(long)q0 * 20 + l10 * 2];
                float4 a1 = featf[(long)q0 * 20 + l10 * 2 + 1];
                float4 b0 = featf[(long)q1 * 20 + l10 * 2];
                float4 b1 = featf[(long)q1 * 20 + l10 * 2 + 1];
                acc[0] += d0 * a0.x; acc[1] += d0 * a0.y;
                acc[2] += d0 * a0.z; acc[3] += d0 * a0.w;
                acc[4] += d0 * a1.x; acc[5] += d0 * a1.y;
                acc[6] += d0 * a1.z; acc[7] += d0 * a1.w;
                acc[0] += d1 * b0.x; acc[1] += d1 * b0.y;
                acc[2] += d1 * b0.z; acc[3] += d1 * b0.w;
                acc[4] += d1 * b1.x; acc[5] += d1 * b1.y;
                acc[6] += d1 * b1.z; acc[7] += d1 * b1.w;
            }
        }
        for (; i < len; i += SPLITS) {
            int p = start + i;
            float d = FAST ? dgath[p] : depth[rd[p]];
            int q = rf[p];
            if (FAST) {
                bf8_fma(acc, d, fbf[(long)q * NL + l10]);
            } else {
                float4 a0 = featf[(long)q * 20 + l10 * 2];
                float4 a1 = featf[(long)q * 20 + l10 * 2 + 1];
                acc[0] += d * a0.x; acc[1] += d * a0.y;
                acc[2] += d * a0.z; acc[3] += d * a0.w;
                acc[4] += d * a1.x; acc[5] += d * a1.y;
                acc[6] += d * a1.z; acc[7] += d * a1.w;
            }
        }
    }

    #pragma unroll
    for (int j = 0; j < 8; ++j) red[il][split][l10][j] = acc[j];
    __syncthreads();

    if (valid && split == 0) {
        float s[8];
        #pragma unroll
        for (int j = 0; j < 8; ++j) s[j] = acc[j];
        #pragma unroll
        for (int k = 1; k < SPLITS; ++k) {
            #pragma unroll
            for (int j = 0; j < 8; ++j) s[j] += red[il][k][l10][j];
        }
        long ob = (long)(l10 * 8) * n_bev + bev;
        #pragma unroll
        for (int j = 0; j < 8; ++j) out[ob + (long)j * n_bev] = s[j];
    }
}

extern "C" void kernel_launch(void* const* d_in, const int* in_sizes, int n_in,
                              void* d_out, int out_size, void* d_ws, size_t ws_size,
                              hipStream_t stream) {
    const float*  depth = (const float*)d_in[0];
    const float4* feat4 = (const float4*)d_in[1];
    const int* ranks_depth = (const int*)d_in[2];
    const int* ranks_feat  = (const int*)d_in[3];
    const int* ranks_bev   = (const int*)d_in[4];
    // d_in[5] = bev_feat_shape (static)
    const int* interval_starts  = (const int*)d_in[6];
    const int* interval_lengths = (const int*)d_in[7];

    int P   = in_sizes[2];               // 1,000,000
    int NF  = in_sizes[1];               // 1,351,680 floats
    int NF4 = NF / 4;                    // 337,920 float4s
    int n_intervals = in_sizes[6];
    int n_bev = out_size / C_CH;         // 16384
    float* out = (float*)d_out;

    size_t dg_bytes  = ((size_t)P * sizeof(float) + 15) & ~(size_t)15;
    size_t fbf_bytes = (size_t)NF * 2;
    bool fast = ws_size >= dg_bytes + fbf_bytes;

    float* dgath = (float*)d_ws;
    uint2* fbf   = (uint2*)((char*)d_ws + dg_bytes);

    // Zero output: uncovered BEV cells must read 0 (harness poisons 0xAA).
    hipMemsetAsync(d_out, 0, (size_t)out_size * sizeof(float), stream);

    if (fast) {
        int n = P > NF4 ? P : NF4;
        int gblock = 256;
        int ggrid = (n + gblock - 1) / gblock;
        prep_kernel<<<ggrid, gblock, 0, stream>>>(depth, ranks_depth, feat4,
                                                  dgath, fbf, P, NF4);
    }

    int grid = (n_intervals + IPB - 1) / IPB;
    if (fast) {
        bev_main<true><<<grid, BLOCK, 0, stream>>>(
            depth, ranks_depth, dgath, (const int4*)fbf, feat4,
            ranks_feat, ranks_bev, interval_starts, interval_lengths,
            n_intervals, n_bev, out);
    } else {
        bev_main<false><<<grid, BLOCK, 0, stream>>>(
            depth, ranks_depth, dgath, (const int4*)fbf, feat4,
            ranks_feat, ranks_bev, interval_starts, interval_lengths,
            n_intervals, n_bev, out);
    }
}